// Round 1
// baseline (1095.064 us; speedup 1.0000x reference)
//
#include <hip/hip_runtime.h>

typedef float  f32x4 __attribute__((ext_vector_type(4)));
typedef short  s16x8 __attribute__((ext_vector_type(8)));

#define AS1 __attribute__((address_space(1)))
#define AS3 __attribute__((address_space(3)))

__device__ __forceinline__ void gload_lds16(const void* g, void* l) {
  __builtin_amdgcn_global_load_lds((AS1 void*)(g), (AS3 void*)(l), 16, 0, 0);
}

__device__ __forceinline__ void mfma_bf16(f32x4& d, s16x8 a, s16x8 b) {
  asm volatile("v_mfma_f32_16x16x32_bf16 %0, %1, %2, %0" : "+v"(d) : "v"(a), "v"(b));
}

__device__ __forceinline__ unsigned short f2bf(float f) {
  union { float f; unsigned u; } v; v.f = f;
  unsigned u = v.u;
  unsigned r = u + 0x7fffu + ((u >> 16) & 1u);   // round-to-nearest-even
  return (unsigned short)(r >> 16);
}

// ---------------- fp32 -> bf16 convert (grid-stride, float4 loads) ----------------
__launch_bounds__(256)
__global__ void cvt_bf16(const float* __restrict__ in, unsigned short* __restrict__ out, int n4) {
  for (int i = blockIdx.x * blockDim.x + threadIdx.x; i < n4; i += gridDim.x * blockDim.x) {
    float4 v = ((const float4*)in)[i];
    ushort4 u;
    u.x = f2bf(v.x); u.y = f2bf(v.y); u.z = f2bf(v.z); u.w = f2bf(v.w);
    ((ushort4*)out)[i] = u;
  }
}

// ---------------- h0 init: copy fp32 + bf16 ----------------
__launch_bounds__(256)
__global__ void init_h(const float* __restrict__ hid, float* __restrict__ hA,
                       unsigned short* __restrict__ hbf) {
  int i = blockIdx.x * 256 + threadIdx.x;      // 64*256 = 16384 float4 = 65536 elems
  float4 v = ((const float4*)hid)[i];
  ((float4*)hA)[i] = v;
  ushort4 u; u.x = f2bf(v.x); u.y = f2bf(v.y); u.z = f2bf(v.z); u.w = f2bf(v.w);
  ((ushort4*)hbf)[i] = u;
}

// ---------------- embedding gather + relu -> bf16 ----------------
// grid: 2048 blocks (one per (t,b)), 256 threads x 4 floats = H=1024
__launch_bounds__(256)
__global__ void embed_relu(const int* __restrict__ tgt, const float* __restrict__ emb,
                           unsigned short* __restrict__ xbf) {
  int bid = blockIdx.x;
  int t = bid >> 6, b = bid & 63;
  int tok = (t == 0) ? 1 : tgt[(t - 1) * 64 + b];
  int c = threadIdx.x;
  float4 v = ((const float4*)(emb + (size_t)tok * 1024))[c];
  v.x = fmaxf(v.x, 0.f); v.y = fmaxf(v.y, 0.f); v.z = fmaxf(v.z, 0.f); v.w = fmaxf(v.w, 0.f);
  ushort4 u; u.x = f2bf(v.x); u.y = f2bf(v.y); u.z = f2bf(v.z); u.w = f2bf(v.w);
  ((ushort4*)(xbf + (size_t)bid * 1024))[c] = u;
}

// ---------------- bf16 MFMA GEMM:  C[M,N] = A[M,K] @ B[N,K]^T + bias ----------------
// 128x128 tile, BK=32, 4 waves (2x2 of 64x64), m97-style global_load_lds staging.
// STATS: also emit per-(row, n-tile) (max, sumexp) partials for log_softmax.
template<bool STATS>
__launch_bounds__(256)
__global__ void gemm_bt(const unsigned short* __restrict__ A,   // [M,K] bf16
                        const unsigned short* __restrict__ B,   // [N,K] bf16
                        const float* __restrict__ bias,         // [N] fp32
                        float* __restrict__ C,                  // [M,N] fp32
                        float2* __restrict__ stats,             // [M, nTilesTotal]
                        int N, int K, int mTiles, int nTilesTotal) {
  __shared__ unsigned short As[128 * 32];
  __shared__ unsigned short Bs[128 * 32];
  __shared__ float2 sstat[2][128];

  const int tid = threadIdx.x;
  const int bid = blockIdx.x;
  const int tileN = bid / mTiles;          // N-major: 16 consecutive blocks share B panel
  const int tileM = bid % mTiles;
  const int m0 = tileM * 128, n0 = tileN * 128;
  const int lane = tid & 63;
  const int w = tid >> 6, wr = w >> 1, wc = w & 1;
  const int lr = lane & 15, lg = lane >> 4;

  f32x4 acc[4][4];
#pragma unroll
  for (int m = 0; m < 4; ++m)
#pragma unroll
    for (int n = 0; n < 4; ++n) acc[m][n] = (f32x4){0.f, 0.f, 0.f, 0.f};

  const int arow = tid >> 2;          // 0..63
  const int k8 = (tid & 3) * 8;       // element offset 0,8,16,24

  for (int kt = 0; kt < K; kt += 32) {
#pragma unroll
    for (int c = 0; c < 2; ++c) {
      gload_lds16(A + (size_t)(m0 + arow + c * 64) * K + kt + k8, &As[(arow + c * 64) * 32 + k8]);
      gload_lds16(B + (size_t)(n0 + arow + c * 64) * K + kt + k8, &Bs[(arow + c * 64) * 32 + k8]);
    }
    __syncthreads();   // drains vmcnt: LDS tiles ready
    s16x8 af[4], bfr[4];
#pragma unroll
    for (int m = 0; m < 4; ++m)
      af[m] = *reinterpret_cast<const s16x8*>(&As[(wr * 64 + m * 16 + lr) * 32 + lg * 8]);
#pragma unroll
    for (int n = 0; n < 4; ++n)
      bfr[n] = *reinterpret_cast<const s16x8*>(&Bs[(wc * 64 + n * 16 + lr) * 32 + lg * 8]);
#pragma unroll
    for (int m = 0; m < 4; ++m)
#pragma unroll
      for (int n = 0; n < 4; ++n) mfma_bf16(acc[m][n], af[m], bfr[n]);
    __syncthreads();   // all reads retired before next-tile overwrite
  }

  // bias add
  float bv[4];
#pragma unroll
  for (int n = 0; n < 4; ++n) bv[n] = bias[n0 + wc * 64 + n * 16 + lr];
#pragma unroll
  for (int m = 0; m < 4; ++m)
#pragma unroll
    for (int n = 0; n < 4; ++n)
#pragma unroll
      for (int j = 0; j < 4; ++j) acc[m][n][j] += bv[n];

  // store C  (C/D frag: col = lane&15, row = (lane>>4)*4 + reg)
#pragma unroll
  for (int m = 0; m < 4; ++m) {
    int rbase = m0 + wr * 64 + m * 16 + lg * 4;
#pragma unroll
    for (int j = 0; j < 4; ++j) {
      size_t roff = (size_t)(rbase + j) * N;
#pragma unroll
      for (int n = 0; n < 4; ++n)
        C[roff + n0 + wc * 64 + n * 16 + lr] = acc[m][n][j];
    }
  }

  if (STATS) {
    // per-row (max, sumexp) over this wave's 64 cols, then combine the two wc halves
#pragma unroll
    for (int m = 0; m < 4; ++m) {
#pragma unroll
      for (int j = 0; j < 4; ++j) {
        float vmax = acc[m][0][j];
#pragma unroll
        for (int n = 1; n < 4; ++n) vmax = fmaxf(vmax, acc[m][n][j]);
#pragma unroll
        for (int s = 1; s < 16; s <<= 1) vmax = fmaxf(vmax, __shfl_xor(vmax, s, 64));
        float ss = 0.f;
#pragma unroll
        for (int n = 0; n < 4; ++n) ss += __expf(acc[m][n][j] - vmax);
#pragma unroll
        for (int s = 1; s < 16; s <<= 1) ss += __shfl_xor(ss, s, 64);
        if (lr == 0) sstat[wc][wr * 64 + m * 16 + lg * 4 + j] = make_float2(vmax, ss);
      }
    }
    __syncthreads();
    if (tid < 128) {
      float2 a = sstat[0][tid], b = sstat[1][tid];
      float Mx = fmaxf(a.x, b.x);
      float S = a.y * __expf(a.x - Mx) + b.y * __expf(b.x - Mx);
      stats[(size_t)(m0 + tid) * nTilesTotal + tileN] = make_float2(Mx, S);
    }
  }
}

// ---------------- fused GRU step: gh = h@w_hh^T (+b_hh), gates, h_new ----------------
// grid: 64 blocks (16 output cols each), 4 waves (16 batch rows each).
// Register-direct MFMA frag loads from global (no LDS, no barriers) — w_hh stays L2-hot.
__launch_bounds__(256)
__global__ void gru_step(const unsigned short* __restrict__ hbf_in,   // [64,1024] bf16
                         const unsigned short* __restrict__ whh,      // [3072,1024] bf16
                         const float* __restrict__ gi,                // [64,3072] (this step)
                         const float* __restrict__ bhh,               // [3072]
                         const float* __restrict__ h_in,              // [64,1024] fp32
                         float* __restrict__ h_out,                   // [64,1024] fp32
                         unsigned short* __restrict__ hbf_out) {      // [64,1024] bf16
  const int tid = threadIdx.x, lane = tid & 63, w = tid >> 6;
  const int lr = lane & 15, lg = lane >> 4;
  const int j0 = blockIdx.x * 16;

  f32x4 acc[3];
#pragma unroll
  for (int g = 0; g < 3; ++g) acc[g] = (f32x4){0.f, 0.f, 0.f, 0.f};

#pragma unroll 4
  for (int kt = 0; kt < 1024; kt += 32) {
    s16x8 a = *reinterpret_cast<const s16x8*>(&hbf_in[(size_t)(w * 16 + lr) * 1024 + kt + lg * 8]);
#pragma unroll
    for (int g = 0; g < 3; ++g) {
      s16x8 bfr = *reinterpret_cast<const s16x8*>(&whh[(size_t)(g * 1024 + j0 + lr) * 1024 + kt + lg * 8]);
      mfma_bf16(acc[g], a, bfr);
    }
  }

  const int col = j0 + lr;
#pragma unroll
  for (int j = 0; j < 4; ++j) {
    int b = w * 16 + lg * 4 + j;
    size_t gbase = (size_t)b * 3072 + col;
    float gr = acc[0][j] + bhh[col];
    float gz = acc[1][j] + bhh[1024 + col];
    float gn = acc[2][j] + bhh[2048 + col];
    float r = 1.f / (1.f + __expf(-(gi[gbase] + gr)));
    float z = 1.f / (1.f + __expf(-(gi[gbase + 1024] + gz)));
    float n = tanhf(gi[gbase + 2048] + r * gn);
    float hnew = (1.f - z) * n + z * h_in[(size_t)b * 1024 + col];
    h_out[(size_t)b * 1024 + col] = hnew;
    hbf_out[(size_t)b * 1024 + col] = f2bf(hnew);
  }
}

// ---------------- per-row logZ from tile partials (one wave per row) ----------------
__launch_bounds__(256)
__global__ void reduce_logz(const float2* __restrict__ stats, float* __restrict__ logZ, int nt) {
  int gid = blockIdx.x * blockDim.x + threadIdx.x;
  int row = gid >> 6, lane = gid & 63;
  const float2* s = stats + (size_t)row * nt;
  float M = -3.4e38f;
  for (int i = lane; i < nt; i += 64) M = fmaxf(M, s[i].x);
#pragma unroll
  for (int sh = 1; sh < 64; sh <<= 1) M = fmaxf(M, __shfl_xor(M, sh, 64));
  float S = 0.f;
  for (int i = lane; i < nt; i += 64) S += s[i].y * __expf(s[i].x - M);
#pragma unroll
  for (int sh = 1; sh < 64; sh <<= 1) S += __shfl_xor(S, sh, 64);
  if (lane == 0) logZ[row] = M + logf(S);
}

// ---------------- fixup: out[row, v] -= logZ[row] ----------------
__launch_bounds__(256)
__global__ void fixup_ls(float* __restrict__ out, const float* __restrict__ logZ) {
  const size_t total4 = 65536000u / 4u;
  for (size_t i = blockIdx.x * (size_t)blockDim.x + threadIdx.x; i < total4;
       i += (size_t)gridDim.x * blockDim.x) {
    float4 v = ((float4*)out)[i];
    int row = (int)((i * 4) / 32000);
    float z = logZ[row];
    v.x -= z; v.y -= z; v.z -= z; v.w -= z;
    ((float4*)out)[i] = v;
  }
}

// ---------------- h_last copy ----------------
__launch_bounds__(256)
__global__ void copy_h(const float* __restrict__ src, float* __restrict__ dst) {
  int i = blockIdx.x * 256 + threadIdx.x;   // 64*256 = 16384 float4
  ((float4*)dst)[i] = ((const float4*)src)[i];
}

extern "C" void kernel_launch(void* const* d_in, const int* in_sizes, int n_in,
                              void* d_out, int out_size, void* d_ws, size_t ws_size,
                              hipStream_t stream) {
  const int*   target = (const int*)d_in[0];
  // d_in[1] = encoder_outputs: unused by the reference computation
  const float* hidden = (const float*)d_in[2];
  const float* emb    = (const float*)d_in[3];
  const float* wih    = (const float*)d_in[4];
  const float* whh    = (const float*)d_in[5];
  const float* bih    = (const float*)d_in[6];
  const float* bhh    = (const float*)d_in[7];
  const float* fcw    = (const float*)d_in[8];
  const float* fcb    = (const float*)d_in[9];
  float* out = (float*)d_out;

  const int L = 32, B = 64, H = 1024, V = 32000;
  const int LB = L * B;                 // 2048
  const int NT_LOGITS = V / 128;        // 250
  const int MT = LB / 128;              // 16

  char* ws = (char*)d_ws;
  size_t off = 0;
  auto alloc = [&](size_t bytes) -> void* {
    void* p = ws + off;
    off += (bytes + 255) & ~(size_t)255;
    return p;
  };
  unsigned short* wih_bf  = (unsigned short*)alloc((size_t)3 * H * H * 2);       // 6 MB
  unsigned short* whh_bf  = (unsigned short*)alloc((size_t)3 * H * H * 2);       // 6 MB
  unsigned short* fcw_bf  = (unsigned short*)alloc((size_t)V * H * 2);           // 65.5 MB
  unsigned short* x_bf    = (unsigned short*)alloc((size_t)LB * H * 2);          // 4 MB
  unsigned short* outs_bf = (unsigned short*)alloc((size_t)(L + 1) * B * H * 2); // 4.3 MB (slot 0 = h0)
  float*          gi      = (float*)alloc((size_t)LB * 3 * H * 4);               // 25 MB
  float*          hA      = (float*)alloc((size_t)B * H * 4);
  float*          hB      = (float*)alloc((size_t)B * H * 4);
  float2*         stats   = (float2*)alloc((size_t)LB * NT_LOGITS * 8);          // 4 MB
  float*          logZ    = (float*)alloc((size_t)LB * 4);
  (void)ws_size; (void)in_sizes; (void)n_in; (void)out_size;

  // weights -> bf16
  cvt_bf16<<<2048, 256, 0, stream>>>(wih, wih_bf, 3 * H * H / 4);
  cvt_bf16<<<2048, 256, 0, stream>>>(whh, whh_bf, 3 * H * H / 4);
  cvt_bf16<<<2048, 256, 0, stream>>>(fcw, fcw_bf, V * H / 4);

  // h0
  init_h<<<64, 256, 0, stream>>>(hidden, hA, outs_bf);

  // x = relu(emb[tokens]) -> bf16
  embed_relu<<<LB, 256, 0, stream>>>(target, emb, x_bf);

  // gi = x @ w_ih^T + b_ih   (M=2048, N=3072, K=1024)
  gemm_bt<false><<<(3 * H / 128) * MT, 256, 0, stream>>>(
      x_bf, wih_bf, bih, gi, nullptr, 3 * H, H, MT, 3 * H / 128);

  // GRU scan: 32 fused step kernels
  for (int t = 0; t < L; ++t) {
    const float* hin = (t & 1) ? hB : hA;
    float* hout      = (t & 1) ? hA : hB;
    gru_step<<<64, 256, 0, stream>>>(
        outs_bf + (size_t)t * B * H, whh_bf, gi + (size_t)t * B * 3 * H,
        bhh, hin, hout, outs_bf + (size_t)(t + 1) * B * H);
  }

  // logits = outs @ fc_w^T + fc_b, with per-tile softmax partials (M=2048, N=32000)
  gemm_bt<true><<<NT_LOGITS * MT, 256, 0, stream>>>(
      outs_bf + (size_t)B * H, fcw_bf, fcb, out, stats, V, H, MT, NT_LOGITS);

  // per-row logZ, then log_softmax fixup
  reduce_logz<<<LB * 64 / 256, 256, 0, stream>>>(stats, logZ, NT_LOGITS);
  fixup_ls<<<2048, 256, 0, stream>>>(out, logZ);

  // h_last (after t=31 the fp32 state is in hA)
  copy_h<<<64, 256, 0, stream>>>(hA, out + (size_t)LB * V);
}

// Round 2
// 861.065 us; speedup vs baseline: 1.2718x; 1.2718x over previous
//
#include <hip/hip_runtime.h>

typedef float  f32x4 __attribute__((ext_vector_type(4)));
typedef short  s16x8 __attribute__((ext_vector_type(8)));

#define AS1 __attribute__((address_space(1)))
#define AS3 __attribute__((address_space(3)))

__device__ __forceinline__ void gload_lds16(const void* g, void* l) {
  __builtin_amdgcn_global_load_lds((AS1 void*)(g), (AS3 void*)(l), 16, 0, 0);
}

__device__ __forceinline__ void mfma_bf16(f32x4& d, s16x8 a, s16x8 b) {
  asm volatile("v_mfma_f32_16x16x32_bf16 %0, %1, %2, %0" : "+v"(d) : "v"(a), "v"(b));
}

__device__ __forceinline__ unsigned short f2bf(float f) {
  union { float f; unsigned u; } v; v.f = f;
  unsigned u = v.u;
  unsigned r = u + 0x7fffu + ((u >> 16) & 1u);   // round-to-nearest-even
  return (unsigned short)(r >> 16);
}
__device__ __forceinline__ float bf2f(unsigned short u) {
  union { unsigned u; float f; } v; v.u = ((unsigned)u) << 16; return v.f;
}

// ---------------- fp32 -> bf16 convert ----------------
__launch_bounds__(256)
__global__ void cvt_bf16(const float* __restrict__ in, unsigned short* __restrict__ out, int n4) {
  for (int i = blockIdx.x * blockDim.x + threadIdx.x; i < n4; i += gridDim.x * blockDim.x) {
    float4 v = ((const float4*)in)[i];
    ushort4 u;
    u.x = f2bf(v.x); u.y = f2bf(v.y); u.z = f2bf(v.z); u.w = f2bf(v.w);
    ((ushort4*)out)[i] = u;
  }
}

// ---------------- h0 init: copy fp32 + bf16 ----------------
__launch_bounds__(256)
__global__ void init_h(const float* __restrict__ hid, float* __restrict__ hA,
                       unsigned short* __restrict__ hbf) {
  int i = blockIdx.x * 256 + threadIdx.x;      // 64*256 = 16384 float4 = 65536 elems
  float4 v = ((const float4*)hid)[i];
  ((float4*)hA)[i] = v;
  ushort4 u; u.x = f2bf(v.x); u.y = f2bf(v.y); u.z = f2bf(v.z); u.w = f2bf(v.w);
  ((ushort4*)hbf)[i] = u;
}

// ---------------- embedding gather + relu -> bf16 ----------------
__launch_bounds__(256)
__global__ void embed_relu(const int* __restrict__ tgt, const float* __restrict__ emb,
                           unsigned short* __restrict__ xbf) {
  int bid = blockIdx.x;
  int t = bid >> 6, b = bid & 63;
  int tok = (t == 0) ? 1 : tgt[(t - 1) * 64 + b];
  int c = threadIdx.x;
  float4 v = ((const float4*)(emb + (size_t)tok * 1024))[c];
  v.x = fmaxf(v.x, 0.f); v.y = fmaxf(v.y, 0.f); v.z = fmaxf(v.z, 0.f); v.w = fmaxf(v.w, 0.f);
  ushort4 u; u.x = f2bf(v.x); u.y = f2bf(v.y); u.z = f2bf(v.z); u.w = f2bf(v.w);
  ((ushort4*)(xbf + (size_t)bid * 1024))[c] = u;
}

// ---------------- bf16 MFMA GEMM:  C[M,N] = A[M,K] @ B[N,K]^T + bias ----------------
// 128x128 tile, BK=32, 4 waves, global_load_lds staging, bijective XCD swizzle.
// STATS: per-(row, n-tile) (max, sumexp) partials. OUTBF: write bf16 logits to Cb.
template<bool STATS, bool OUTBF>
__launch_bounds__(256)
__global__ void gemm_bt(const unsigned short* __restrict__ A,   // [M,K] bf16
                        const unsigned short* __restrict__ B,   // [N,K] bf16
                        const float* __restrict__ bias,         // [N] fp32
                        float* __restrict__ Cf,                 // [M,N] fp32 (if !OUTBF)
                        unsigned short* __restrict__ Cb,        // [M,N] bf16 (if OUTBF)
                        float2* __restrict__ stats,             // [M, nTilesTotal]
                        int N, int K, int mTiles, int nTilesTotal) {
  __shared__ unsigned short As[128 * 32];
  __shared__ unsigned short Bs[128 * 32];
  __shared__ float2 sstat[2][128];

  const int tid = threadIdx.x;
  int bid = blockIdx.x;
  { // XCD swizzle (gridDim.x % 8 == 0 for all our launches)
    int q = gridDim.x >> 3;
    bid = (bid & 7) * q + (bid >> 3);
  }
  const int tileN = bid / mTiles;
  const int tileM = bid % mTiles;
  const int m0 = tileM * 128, n0 = tileN * 128;
  const int lane = tid & 63;
  const int w = tid >> 6, wr = w >> 1, wc = w & 1;
  const int lr = lane & 15, lg = lane >> 4;

  f32x4 acc[4][4];
#pragma unroll
  for (int m = 0; m < 4; ++m)
#pragma unroll
    for (int n = 0; n < 4; ++n) acc[m][n] = (f32x4){0.f, 0.f, 0.f, 0.f};

  const int arow = tid >> 2;
  const int k8 = (tid & 3) * 8;

  for (int kt = 0; kt < K; kt += 32) {
#pragma unroll
    for (int c = 0; c < 2; ++c) {
      gload_lds16(A + (size_t)(m0 + arow + c * 64) * K + kt + k8, &As[(arow + c * 64) * 32 + k8]);
      gload_lds16(B + (size_t)(n0 + arow + c * 64) * K + kt + k8, &Bs[(arow + c * 64) * 32 + k8]);
    }
    __syncthreads();
    s16x8 af[4], bfr[4];
#pragma unroll
    for (int m = 0; m < 4; ++m)
      af[m] = *reinterpret_cast<const s16x8*>(&As[(wr * 64 + m * 16 + lr) * 32 + lg * 8]);
#pragma unroll
    for (int n = 0; n < 4; ++n)
      bfr[n] = *reinterpret_cast<const s16x8*>(&Bs[(wc * 64 + n * 16 + lr) * 32 + lg * 8]);
#pragma unroll
    for (int m = 0; m < 4; ++m)
#pragma unroll
      for (int n = 0; n < 4; ++n) mfma_bf16(acc[m][n], af[m], bfr[n]);
    __syncthreads();
  }

  float bv[4];
#pragma unroll
  for (int n = 0; n < 4; ++n) bv[n] = bias[n0 + wc * 64 + n * 16 + lr];
#pragma unroll
  for (int m = 0; m < 4; ++m)
#pragma unroll
    for (int n = 0; n < 4; ++n)
#pragma unroll
      for (int j = 0; j < 4; ++j) acc[m][n][j] += bv[n];

  // store C  (C/D frag: col = lane&15, row = (lane>>4)*4 + reg)
#pragma unroll
  for (int m = 0; m < 4; ++m) {
    int rbase = m0 + wr * 64 + m * 16 + lg * 4;
#pragma unroll
    for (int j = 0; j < 4; ++j) {
      size_t roff = (size_t)(rbase + j) * N;
#pragma unroll
      for (int n = 0; n < 4; ++n) {
        size_t idx = roff + n0 + wc * 64 + n * 16 + lr;
        if (OUTBF) Cb[idx] = f2bf(acc[m][n][j]);
        else       Cf[idx] = acc[m][n][j];
      }
    }
  }

  if (STATS) {
#pragma unroll
    for (int m = 0; m < 4; ++m) {
#pragma unroll
      for (int j = 0; j < 4; ++j) {
        float vmax = acc[m][0][j];
#pragma unroll
        for (int n = 1; n < 4; ++n) vmax = fmaxf(vmax, acc[m][n][j]);
#pragma unroll
        for (int s = 1; s < 16; s <<= 1) vmax = fmaxf(vmax, __shfl_xor(vmax, s, 64));
        float ss = 0.f;
#pragma unroll
        for (int n = 0; n < 4; ++n) ss += __expf(acc[m][n][j] - vmax);
#pragma unroll
        for (int s = 1; s < 16; s <<= 1) ss += __shfl_xor(ss, s, 64);
        if (lr == 0) sstat[wc][wr * 64 + m * 16 + lg * 4 + j] = make_float2(vmax, ss);
      }
    }
    __syncthreads();
    if (tid < 128) {
      float2 a = sstat[0][tid], b = sstat[1][tid];
      float Mx = fmaxf(a.x, b.x);
      float S = a.y * __expf(a.x - Mx) + b.y * __expf(b.x - Mx);
      stats[(size_t)(m0 + tid) * nTilesTotal + tileN] = make_float2(Mx, S);
    }
  }
}

// ---------------- persistent GRU scan: all 32 steps in one kernel ----------------
// 64 blocks (1/CU, co-resident) x 256 threads. Block owns 16 cols of each gate.
// whh panel (48 rows x 1024 bf16 = 96 KB) staged once in LDS, XOR-swizzled
// (row stride 2048 B would be a 16-way bank conflict; byte ^= (row&7)<<4 fixes it).
// Device-scope atomic grid barrier between steps; outs_bf slot rotation means every
// line is read exactly once after its fenced write (no stale-L1 hazard).
__launch_bounds__(256)
__global__ void gru_scan(const unsigned short* __restrict__ whh,  // [3072,1024] bf16
                         const float* __restrict__ gi,            // [32*64, 3072] fp32
                         const float* __restrict__ bhh,           // [3072]
                         float* __restrict__ h,                   // [64,1024] fp32 (in-place, pre-init h0)
                         unsigned short* __restrict__ outs_bf,    // [(L+1)*64*1024], slot0 = h0
                         unsigned* __restrict__ bar) {            // zeroed before launch
  __shared__ char lds[96 * 1024];
  const int tid = threadIdx.x, lane = tid & 63, w = tid >> 6;
  const int lr = lane & 15, lg = lane >> 4;
  const int j0 = blockIdx.x * 16;

  // stage whh panel: rows {g*1024 + j0 + r}, r=0..15, g=0..2  -> lds rows 0..47
  for (int c = tid; c < 6144; c += 256) {        // 6144 x 16B chunks
    int row = c >> 7;                            // 128 chunks per row
    int cb  = (c & 127) << 4;                    // byte offset in row
    int g = row >> 4, r = row & 15;
    s16x8 v = *reinterpret_cast<const s16x8*>(whh + (size_t)(g * 1024 + j0 + r) * 1024 + (cb >> 1));
    *reinterpret_cast<s16x8*>(lds + row * 2048 + (cb ^ ((row & 7) << 4))) = v;
  }

  const int col = j0 + lr;
  const float b_r = bhh[col], b_z = bhh[1024 + col], b_n = bhh[2048 + col];
  int rbase[3], xm[3];
#pragma unroll
  for (int g = 0; g < 3; ++g) {
    int row = g * 16 + lr;
    rbase[g] = row * 2048;
    xm[g] = (row & 7) << 4;
  }
  const int koff = lg * 16;   // byte offset for k = lg*8 elems

  __syncthreads();

  for (int t = 0; t < 32; ++t) {
    const unsigned short* hbf = outs_bf + (size_t)t * 65536;
    f32x4 acc[3];
#pragma unroll
    for (int g = 0; g < 3; ++g) acc[g] = (f32x4){0.f, 0.f, 0.f, 0.f};

#pragma unroll 4
    for (int kt = 0; kt < 1024; kt += 32) {
      s16x8 a = *reinterpret_cast<const s16x8*>(hbf + (size_t)(w * 16 + lr) * 1024 + kt + lg * 8);
#pragma unroll
      for (int g = 0; g < 3; ++g) {
        s16x8 b = *reinterpret_cast<const s16x8*>(lds + rbase[g] + (((kt << 1) + koff) ^ xm[g]));
        mfma_bf16(acc[g], a, b);
      }
    }

    unsigned short* hbf_out = outs_bf + (size_t)(t + 1) * 65536;
#pragma unroll
    for (int j = 0; j < 4; ++j) {
      int b = w * 16 + lg * 4 + j;
      size_t gbase = (size_t)(t * 64 + b) * 3072 + col;
      float hr = acc[0][j] + b_r, hz = acc[1][j] + b_z, hn = acc[2][j] + b_n;
      float r = 1.f / (1.f + __expf(-(gi[gbase] + hr)));
      float z = 1.f / (1.f + __expf(-(gi[gbase + 1024] + hz)));
      float n = tanhf(gi[gbase + 2048] + r * hn);
      size_t hidx = (size_t)b * 1024 + col;
      float hnew = n + z * (h[hidx] - n);
      h[hidx] = hnew;
      hbf_out[hidx] = f2bf(hnew);
    }

    // grid barrier: release-accumulate, acquire-spin
    __syncthreads();
    if (tid == 0) {
      __hip_atomic_fetch_add(bar, 1u, __ATOMIC_ACQ_REL, __HIP_MEMORY_SCOPE_AGENT);
      unsigned target = 64u * (unsigned)(t + 1);
      while (__hip_atomic_load(bar, __ATOMIC_ACQUIRE, __HIP_MEMORY_SCOPE_AGENT) < target)
        __builtin_amdgcn_s_sleep(2);
    }
    __syncthreads();
  }
}

// ---------------- per-row logZ from tile partials ----------------
__launch_bounds__(256)
__global__ void reduce_logz(const float2* __restrict__ stats, float* __restrict__ logZ, int nt) {
  int gid = blockIdx.x * blockDim.x + threadIdx.x;
  int row = gid >> 6, lane = gid & 63;
  const float2* s = stats + (size_t)row * nt;
  float M = -3.4e38f;
  for (int i = lane; i < nt; i += 64) M = fmaxf(M, s[i].x);
#pragma unroll
  for (int sh = 1; sh < 64; sh <<= 1) M = fmaxf(M, __shfl_xor(M, sh, 64));
  float S = 0.f;
  for (int i = lane; i < nt; i += 64) S += s[i].y * __expf(s[i].x - M);
#pragma unroll
  for (int sh = 1; sh < 64; sh <<= 1) S += __shfl_xor(S, sh, 64);
  if (lane == 0) logZ[row] = M + logf(S);
}

// ---------------- fixup (fast path): bf16 logits -> fp32 log_probs ----------------
__launch_bounds__(256)
__global__ void fixup_bf(const unsigned short* __restrict__ lbf, const float* __restrict__ logZ,
                         float* __restrict__ out) {
  const int n8 = 2048 * 32000 / 8;   // 8,192,000
  for (int i = blockIdx.x * 256 + threadIdx.x; i < n8; i += gridDim.x * 256) {
    s16x8 v = reinterpret_cast<const s16x8*>(lbf)[i];
    float z = logZ[i / 4000];
    float4 o0, o1;
    o0.x = bf2f((unsigned short)v[0]) - z; o0.y = bf2f((unsigned short)v[1]) - z;
    o0.z = bf2f((unsigned short)v[2]) - z; o0.w = bf2f((unsigned short)v[3]) - z;
    o1.x = bf2f((unsigned short)v[4]) - z; o1.y = bf2f((unsigned short)v[5]) - z;
    o1.z = bf2f((unsigned short)v[6]) - z; o1.w = bf2f((unsigned short)v[7]) - z;
    reinterpret_cast<float4*>(out)[2 * i]     = o0;
    reinterpret_cast<float4*>(out)[2 * i + 1] = o1;
  }
}

// ---------------- fixup (fallback): in-place RMW on fp32 logits ----------------
__launch_bounds__(256)
__global__ void fixup_rmw(float* __restrict__ out, const float* __restrict__ logZ) {
  const size_t total4 = 65536000u / 4u;
  for (size_t i = blockIdx.x * (size_t)blockDim.x + threadIdx.x; i < total4;
       i += (size_t)gridDim.x * blockDim.x) {
    float4 v = ((float4*)out)[i];
    int row = (int)((i * 4) / 32000);
    float z = logZ[row];
    v.x -= z; v.y -= z; v.z -= z; v.w -= z;
    ((float4*)out)[i] = v;
  }
}

// ---------------- h_last copy ----------------
__launch_bounds__(256)
__global__ void copy_h(const float* __restrict__ src, float* __restrict__ dst) {
  int i = blockIdx.x * 256 + threadIdx.x;
  ((float4*)dst)[i] = ((const float4*)src)[i];
}

extern "C" void kernel_launch(void* const* d_in, const int* in_sizes, int n_in,
                              void* d_out, int out_size, void* d_ws, size_t ws_size,
                              hipStream_t stream) {
  const int*   target = (const int*)d_in[0];
  const float* hidden = (const float*)d_in[2];
  const float* emb    = (const float*)d_in[3];
  const float* wih    = (const float*)d_in[4];
  const float* whh    = (const float*)d_in[5];
  const float* bih    = (const float*)d_in[6];
  const float* bhh    = (const float*)d_in[7];
  const float* fcw    = (const float*)d_in[8];
  const float* fcb    = (const float*)d_in[9];
  float* out = (float*)d_out;

  const int L = 32, B = 64, H = 1024, V = 32000;
  const int LB = L * B;                 // 2048
  const int NT_LOGITS = V / 128;        // 250
  const int MT = LB / 128;              // 16

  char* ws = (char*)d_ws;
  size_t off = 0;
  auto alloc = [&](size_t bytes) -> void* {
    void* p = ws + off;
    off += (bytes + 255) & ~(size_t)255;
    return p;
  };
  unsigned short* wih_bf  = (unsigned short*)alloc((size_t)3 * H * H * 2);
  unsigned short* whh_bf  = (unsigned short*)alloc((size_t)3 * H * H * 2);
  unsigned short* fcw_bf  = (unsigned short*)alloc((size_t)V * H * 2);
  unsigned short* x_bf    = (unsigned short*)alloc((size_t)LB * H * 2);
  unsigned short* outs_bf = (unsigned short*)alloc((size_t)(L + 1) * B * H * 2);
  float*          gi      = (float*)alloc((size_t)LB * 3 * H * 4);
  float*          hA      = (float*)alloc((size_t)B * H * 4);
  float2*         stats   = (float2*)alloc((size_t)LB * NT_LOGITS * 8);
  float*          logZ    = (float*)alloc((size_t)LB * 4);
  unsigned*       bar     = (unsigned*)alloc(256);
  // fast-path bf16 logits buffer (131 MB) — only if workspace allows
  size_t lbf_bytes = (size_t)LB * V * 2;
  unsigned short* lbf = (unsigned short*)(ws + off);
  bool big = (off + lbf_bytes) <= ws_size;
  (void)in_sizes; (void)n_in; (void)out_size;

  // weights -> bf16
  cvt_bf16<<<2048, 256, 0, stream>>>(wih, wih_bf, 3 * H * H / 4);
  cvt_bf16<<<2048, 256, 0, stream>>>(whh, whh_bf, 3 * H * H / 4);
  cvt_bf16<<<2048, 256, 0, stream>>>(fcw, fcw_bf, V * H / 4);

  // h0
  init_h<<<64, 256, 0, stream>>>(hidden, hA, outs_bf);

  // x = relu(emb[tokens]) -> bf16
  embed_relu<<<LB, 256, 0, stream>>>(target, emb, x_bf);

  // gi = x @ w_ih^T + b_ih   (M=2048, N=3072, K=1024); grid 384 (%8==0)
  gemm_bt<false, false><<<(3 * H / 128) * MT, 256, 0, stream>>>(
      x_bf, wih_bf, bih, gi, nullptr, nullptr, 3 * H, H, MT, 3 * H / 128);

  // persistent GRU scan (barrier counter zeroed each call -> deterministic)
  hipMemsetAsync(bar, 0, 4, stream);
  gru_scan<<<64, 256, 0, stream>>>(whh_bf, gi, bhh, hA, outs_bf, bar);

  // logits GEMM (M=2048, N=32000); grid 4000 (%8==0)
  if (big) {
    gemm_bt<true, true><<<NT_LOGITS * MT, 256, 0, stream>>>(
        outs_bf + (size_t)B * H, fcw_bf, fcb, nullptr, lbf, stats, V, H, MT, NT_LOGITS);
    reduce_logz<<<LB * 64 / 256, 256, 0, stream>>>(stats, logZ, NT_LOGITS);
    fixup_bf<<<2048, 256, 0, stream>>>(lbf, logZ, out);
  } else {
    gemm_bt<true, false><<<NT_LOGITS * MT, 256, 0, stream>>>(
        outs_bf + (size_t)B * H, fcw_bf, fcb, out, nullptr, stats, V, H, MT, NT_LOGITS);
    reduce_logz<<<LB * 64 / 256, 256, 0, stream>>>(stats, logZ, NT_LOGITS);
    fixup_rmw<<<2048, 256, 0, stream>>>(out, logZ);
  }

  // h_last
  copy_h<<<64, 256, 0, stream>>>(hA, out + (size_t)LB * V);
}